// Round 13
// baseline (155.196 us; speedup 1.0000x reference)
//
#include <hip/hip_runtime.h>
#include <hip/hip_bf16.h>

#define MSEQ 2048

typedef __attribute__((ext_vector_type(8))) short short8;
typedef __attribute__((ext_vector_type(4))) short short4v;
typedef __attribute__((ext_vector_type(4))) float f32x4;

static __device__ __forceinline__ short bf16b(float f) {
    __hip_bfloat16 h = __float2bfloat16(f);   // RNE
    return *reinterpret_cast<short*>(&h);
}

// raw 2^x (input is pre-scaled by log2e at the K projection)
static __device__ __forceinline__ float fast_exp2(float x) {
    float r;
    asm("v_exp_f32 %0, %1" : "=v"(r) : "v"(x));
    return r;
}

// 16x16x16 bf16 MFMA (DQK=16 exact; score D-layout == PV A-frag layout)
static __device__ __forceinline__ f32x4 mfma16(short4v a, short4v b, f32x4 c) {
    return __builtin_amdgcn_mfma_f32_16x16x16bf16_1k(a, b, c, 0, 0, 0);
}

// async global->LDS, 16B per lane; LDS dest = wave-uniform base + lane*16
static __device__ __forceinline__ void gl_lds16(const void* g, void* l) {
    __builtin_amdgcn_global_load_lds(
        (const __attribute__((address_space(1))) unsigned int*)g,
        (__attribute__((address_space(3))) unsigned int*)l, 16, 0, 0);
}

// ---------------- prep: x fp32->bf16 | W->WT[n][k] bf16 | mask->bf16 ----------------
__global__ __launch_bounds__(256) void prep_kernel(
    const float* __restrict__ x, unsigned short* __restrict__ xb,
    const float* __restrict__ Wq, const float* __restrict__ Wk,
    const float* __restrict__ Wv, unsigned short* __restrict__ WT,
    const int* __restrict__ mask, unsigned short* __restrict__ maskbf)
{
    __shared__ unsigned short Ts[64*72];   // wtrans only
    const int bid = blockIdx.x;
    const int t = threadIdx.x;

    if (bid < 2048) {                      // ---- x cvt ----
        const size_t i = ((size_t)bid * 256 + t) * 8;
        const float4 a = *(const float4*)(x + i);
        const float4 b = *(const float4*)(x + i + 4);
        short8 o;
        o[0]=bf16b(a.x); o[1]=bf16b(a.y); o[2]=bf16b(a.z); o[3]=bf16b(a.w);
        o[4]=bf16b(b.x); o[5]=bf16b(b.y); o[6]=bf16b(b.z); o[7]=bf16b(b.w);
        *(short8*)(xb + i) = o;
        return;
    }
    if (bid == 2144) {                     // ---- mask -> bf16 (0/1 exact) ----
        #pragma unroll
        for (int j = 0; j < 8; ++j) {
            const int4 m4 = *(const int4*)(mask + (t*8 + j)*4);
            short4v o;
            o[0]=bf16b((float)m4.x); o[1]=bf16b((float)m4.y);
            o[2]=bf16b((float)m4.z); o[3]=bf16b((float)m4.w);
            *(short4v*)(maskbf + (t*8 + j)*4) = o;
        }
        return;
    }
    // ---- wtrans ----
    const int idx = bid - 2048;            // 96 blocks
    const int nt = idx >> 3;
    const int kt = idx & 7;
    const int k0 = kt*64;

    const float* W; int ld, n0;
    if (nt < 2)      { W = Wq; ld = 128; n0 = nt*64; }
    else if (nt < 4) { W = Wk; ld = 128; n0 = (nt-2)*64; }
    else             { W = Wv; ld = 512; n0 = (nt-4)*64; }

    #pragma unroll
    for (int s = 0; s < 4; ++s) {
        const int lin = s*256 + t;
        const int krow = lin >> 4, ng = lin & 15;
        const float4 v = *(const float4*)(W + (size_t)(k0+krow)*ld + n0 + ng*4);
        Ts[(ng*4+0)*72 + krow] = (unsigned short)bf16b(v.x);
        Ts[(ng*4+1)*72 + krow] = (unsigned short)bf16b(v.y);
        Ts[(ng*4+2)*72 + krow] = (unsigned short)bf16b(v.z);
        Ts[(ng*4+3)*72 + krow] = (unsigned short)bf16b(v.w);
    }
    __syncthreads();
    #pragma unroll
    for (int s = 0; s < 2; ++s) {
        const int lin = s*256 + t;
        const int nrow = lin >> 3, kg = lin & 7;
        *(short8*)(WT + (size_t)(nt*64 + nrow)*512 + k0 + kg*8) = *(const short8*)&Ts[nrow*72 + kg*8];
    }
}

// ---------------- Fused projection GEMM, bf16 MFMA, 64x128 tiles (r11 verbatim) ----------------
__global__ __launch_bounds__(256, 3) void proj_mfma(
    const unsigned short* __restrict__ xb, const unsigned short* __restrict__ WT,
    const float* __restrict__ bq, const float* __restrict__ bk, const float* __restrict__ bv,
    const int* __restrict__ mask,
    unsigned short* __restrict__ Qb, unsigned short* __restrict__ Kb, unsigned short* __restrict__ Vt)
{
    const int g0 = blockIdx.y * 6 + blockIdx.x;   // 768 blocks, 768%8==0
    const int xcd = g0 & 7, idx = g0 >> 3;        // idx in [0,96)
    const int nt = idx / 16;                      // 0..5 (0=Q,1=K,2..5=V)
    const int r0 = (xcd * 16 + (idx & 15)) * 64;  // m tile (bijective)
    const int n0 = nt * 128;
    const int t = threadIdx.x, w = t >> 6, lane = t & 63, l15 = lane & 15, quad = lane >> 4;
    const int qh = w >> 1, chh = w & 1;

    __shared__ short smem[12288];     // As[2][2048] | Bs[2][4096]; Ts aliases (<=9216)
    short* As = smem;
    short* Bs = smem + 4096;

    f32x4 acc[2][4];
    #pragma unroll
    for (int i = 0; i < 2; ++i)
        #pragma unroll
        for (int j = 0; j < 4; ++j) acc[i][j] = {0.f,0.f,0.f,0.f};

    const int arow = lane >> 2, akg = lane & 3;

#define PROJ_STAGE(BUFI, KK) {                                                          \
    gl_lds16(xb + (size_t)(r0 + w*16 + arow)*512 + (KK) + akg*8,                        \
             (char*)As + (BUFI)*4096 + w*1024);                                         \
    gl_lds16(WT + (size_t)(n0 + w*16 + arow)*512 + (KK) + akg*8,                        \
             (char*)Bs + (BUFI)*8192 + w*1024);                                         \
    gl_lds16(WT + (size_t)(n0 + 64 + w*16 + arow)*512 + (KK) + akg*8,                   \
             (char*)Bs + (BUFI)*8192 + 4096 + w*1024);                                  \
}

    PROJ_STAGE(0, 0)
    __syncthreads();

    #pragma unroll 2
    for (int kp = 0; kp < 16; ++kp) {
        const int cur = kp & 1;
        if (kp < 15) PROJ_STAGE(cur ^ 1, (kp+1)*32)
        short8 Af[2], Bf[4];
        #pragma unroll
        for (int i = 0; i < 2; ++i)
            Af[i] = *(const short8*)&As[cur*2048 + (qh*32 + i*16 + l15)*32 + quad*8];
        #pragma unroll
        for (int j = 0; j < 4; ++j)
            Bf[j] = *(const short8*)&Bs[cur*4096 + (chh*64 + j*16 + l15)*32 + quad*8];
        #pragma unroll
        for (int i = 0; i < 2; ++i)
            #pragma unroll
            for (int j = 0; j < 4; ++j)
                acc[i][j] = __builtin_amdgcn_mfma_f32_16x16x32_bf16(Af[i], Bf[j], acc[i][j], 0, 0, 0);
        __syncthreads();
    }

    const float* bias = (nt == 0) ? bq : (nt == 1) ? bk : (bv + (nt-2)*128);
    const float kscale = (nt == 1) ? 0.36067376022224085f : 1.0f;  // 0.25 * log2(e)
    float bj[4];
    #pragma unroll
    for (int j = 0; j < 4; ++j) bj[j] = bias[chh*64 + j*16 + l15];

    const int bb = r0 >> 11, key0 = r0 & 2047;
    short* Ts = smem;
    if (nt < 2) {
        #pragma unroll
        for (int i = 0; i < 2; ++i)
            #pragma unroll
            for (int j = 0; j < 4; ++j)
                #pragma unroll
                for (int r = 0; r < 4; ++r)
                    Ts[(qh*32 + i*16 + quad*4 + r)*136 + chh*64 + j*16 + l15] =
                        bf16b((acc[i][j][r] + bj[j]) * kscale);
    } else {
        float mv[2][4];
        #pragma unroll
        for (int i = 0; i < 2; ++i)
            #pragma unroll
            for (int r = 0; r < 4; ++r)
                mv[i][r] = (float)mask[bb*MSEQ + key0 + qh*32 + i*16 + quad*4 + r];
        #pragma unroll
        for (int i = 0; i < 2; ++i)
            #pragma unroll
            for (int j = 0; j < 4; ++j)
                #pragma unroll
                for (int r = 0; r < 4; ++r)
                    Ts[(chh*64 + j*16 + l15)*72 + qh*32 + i*16 + quad*4 + r] =
                        bf16b((acc[i][j][r] + bj[j]) * mv[i][r]);
    }
    __syncthreads();

    if (nt < 2) {
        unsigned short* Out = (nt == 0) ? Qb : Kb;
        #pragma unroll
        for (int s = 0; s < 4; ++s) {
            const int lin = s*256 + t, row = lin >> 4, seg = lin & 15;
            *(short8*)(Out + (size_t)(r0+row)*128 + seg*8) = *(const short8*)&Ts[row*136 + seg*8];
        }
    } else {
        const int chBase = (nt-2)*128;
        #pragma unroll
        for (int s = 0; s < 4; ++s) {
            const int lin = s*256 + t, row = lin >> 3, seg = lin & 7;
            *(short8*)(Vt + ((size_t)(bb*512 + chBase + row))*MSEQ + key0 + seg*8) =
                *(const short8*)&Ts[row*72 + seg*8];
        }
    }
#undef PROJ_STAGE
}

// ---------------- Fused masked attention: 8 waves x 32q x 64ch (q-expansion) ----------------
// Round-13 = round-12 resubmitted (r12 bench was an infrastructure failure, no
// kernel evidence). Each wave owns TWO 16-q MFMA groups over all 64 ch; K/V/mask
// frags loaded once per wave, reused by both groups -> LDS read volume and
// staging DMA per q HALVE (the binding pipe, ~30us of r11's 57.5us), while
// exp/MFMA per q stay constant. Block = 256 q (grid 8x32 = 256 = 1/CU);
// launch_bounds(512,2) for the doubled accumulator state (~92 VGPR, no spill).
// Same race-free STAGE(cur^1)->COMPUTE(cur)->__syncthreads skeleton.
__global__ __launch_bounds__(512, 2) void attn_mfma(
    const unsigned short* __restrict__ Qb, const unsigned short* __restrict__ Kb,
    const unsigned short* __restrict__ Vt, const unsigned short* __restrict__ maskbf,
    const float* __restrict__ gamma, float* __restrict__ out)
{
    // XCD-aware bijective remap (256 % 8 == 0): XCD x owns bh in [x*4, x*4+4)
    const int bid = blockIdx.y * 8 + blockIdx.x;   // 256 blocks
    const int lin = (bid & 7) * 32 + (bid >> 3);
    const int mt = lin & 7, bh = lin >> 3;
    const int b  = bh >> 3, h = bh & 7;
    const int m0 = mt * 256;
    const int t  = threadIdx.x;
    const int w = t >> 6, lane = t & 63, l15 = lane & 15, quad = lane >> 4;
    const int mq = m0 + w*32;            // this wave's 32 q rows (2 groups of 16)

    __shared__ __align__(16) short Ks[2][64*16];   // [key][16 d], granule-swizzled
    __shared__ __align__(16) short Vs[2][64*64];   // [ch][64 key], granule-swizzled, pre-masked
    __shared__ __align__(16) short Msb[2][64];     // bf16 mask per key

    // Q B-frags for the two 16-q groups: n=q=l15, k=d=quad*4+j
    short4v qf[2];
    #pragma unroll
    for (int g = 0; g < 2; ++g)
        qf[g] = *(const short4v*)(Qb + (size_t)(b*MSEQ + mq + g*16 + l15)*128 + h*16 + quad*4);

    // staging sources (per-lane, swizzle pre-applied on the global side) — unchanged
    const unsigned short* Kg = Kb + (size_t)(b*MSEQ + (lane>>1))*128 + h*16
                              + (((lane&1) ^ ((lane>>3)&1))*8);
    // wave w stages V ch-rows w*8 .. w*8+7 (one 1KB DMA per wave)
    const unsigned short* Vg = Vt + (size_t)(b*512 + h*64 + w*8 + (lane>>3))*MSEQ
                              + (((lane&7) ^ ((lane>>3)&7)) * 8);
    const unsigned short* Mgb = maskbf + b*MSEQ + lane*8;   // w==2, lanes<8

#define ATT_STAGE(BUFI, KN) {                                                        \
    gl_lds16(Vg + (KN), &Vs[BUFI][w*512]);                                           \
    if (w < 2)                   gl_lds16(Kg + (size_t)((KN) + w*32)*128, &Ks[BUFI][w*32*16]); \
    else if (w == 2 && lane < 8) gl_lds16(Mgb + (KN), &Msb[BUFI][0]);                \
}

    // hoisted LDS read offsets (bytes)
    const char* KsB = (const char*)&Ks[0][0];
    const char* VsB = (const char*)&Vs[0][0];
    const char* MsB = (const char*)&Msb[0][0];
    const int kofs = l15*32 + (((quad>>1) ^ ((l15>>2)&1))*16) + (quad&1)*8;
    const int mofs = quad*8;
    int vb[4];
    #pragma unroll
    for (int v = 0; v < 4; ++v) {
        const int ch = v*16 + l15;
        vb[v] = ch*128 + (((quad>>1) ^ (ch&7))*16) + (quad&1)*8;
    }

    f32x4 O[2][4];      // [q-group][v]
    #pragma unroll
    for (int g = 0; g < 2; ++g)
        #pragma unroll
        for (int v = 0; v < 4; ++v) O[g][v] = {0.f,0.f,0.f,0.f};
    f32x4 WS[2] = {{0.f,0.f,0.f,0.f},{0.f,0.f,0.f,0.f}};

    ATT_STAGE(0, 0)
    __syncthreads();

    #pragma unroll 2
    for (int kt = 0; kt < 32; ++kt) {
        const int cur = kt & 1;
        if (kt < 31) ATT_STAGE(cur ^ 1, (kt+1)*64)

        const char* Kc = KsB + cur*2048;
        const char* Vc = VsB + cur*8192;
        const char* Mc = MsB + cur*128;

        __builtin_amdgcn_s_setprio(1);
        // batch K and mask fragments for all 4 s-slices (independent ds_reads)
        short4v kfs[4], mkfs[4];
        #pragma unroll
        for (int s = 0; s < 4; ++s) {
            kfs[s]  = *(const short4v*)(Kc + kofs + s*512);
            mkfs[s] = *(const short4v*)(Mc + mofs + s*32);
        }

        #pragma unroll
        for (int s = 0; s < 4; ++s) {
            // V fragments once per s-slice; reused by both q-groups (the q-expansion win)
            short4v vfs[4];
            #pragma unroll
            for (int v = 0; v < 4; ++v)
                vfs[v] = *(const short4v*)(Vc + (vb[v] ^ (s*32)));
            #pragma unroll
            for (int g = 0; g < 2; ++g) {
                f32x4 sc = {0.f,0.f,0.f,0.f};
                sc = mfma16(kfs[s], qf[g], sc);
                // lane: q=l15 (group g), keys = s*16+quad*4+r; K pre-scaled by 0.25*log2e
                const float w0 = fast_exp2(fmaxf(sc[0], 0.f));
                const float w1 = fast_exp2(fmaxf(sc[1], 0.f));
                const float w2 = fast_exp2(fmaxf(sc[2], 0.f));
                const float w3 = fast_exp2(fmaxf(sc[3], 0.f));
                const __hip_bfloat162 p01 = __float22bfloat162_rn(make_float2(w0, w1));
                const __hip_bfloat162 p23 = __float22bfloat162_rn(make_float2(w2, w3));
                unsigned u01, u23;
                __builtin_memcpy(&u01, &p01, 4);
                __builtin_memcpy(&u23, &p23, 4);
                uint2 pku; pku.x = u01; pku.y = u23;
                short4v pf;
                __builtin_memcpy(&pf, &pku, 8);
                WS[g] = mfma16(pf, mkfs[s], WS[g]);     // wsum: D row q=quad*4+r on this lane
                #pragma unroll
                for (int v = 0; v < 4; ++v)
                    O[g][v] = mfma16(pf, vfs[v], O[g][v]);   // V pre-masked
            }
        }
        __builtin_amdgcn_s_setprio(0);
        __syncthreads();   // full drain: reads of cur done; stage of cur^1 landed
    }

    // WS[g][r] = masked wsum for q = mq + g*16 + quad*4 + r — same lane that owns O[g][.][r].
    const float gm = gamma[0];
    #pragma unroll
    for (int g = 0; g < 2; ++g) {
        float inv[4];
        #pragma unroll
        for (int r = 0; r < 4; ++r) inv[r] = gm / fmaxf(WS[g][r], 1e-20f);
        float* op = out + (size_t)(b*MSEQ + mq + g*16 + quad*4)*512 + h*64 + l15;
        #pragma unroll
        for (int r = 0; r < 4; ++r) {
            op[(size_t)r*512 +  0] = O[g][0][r] * inv[r];
            op[(size_t)r*512 + 16] = O[g][1][r] * inv[r];
            op[(size_t)r*512 + 32] = O[g][2][r] * inv[r];
            op[(size_t)r*512 + 48] = O[g][3][r] * inv[r];
        }
    }
#undef ATT_STAGE
}

extern "C" void kernel_launch(void* const* d_in, const int* in_sizes, int n_in,
                              void* d_out, int out_size, void* d_ws, size_t ws_size,
                              hipStream_t stream) {
    const float* x     = (const float*)d_in[0];
    const int*   mask  = (const int*)  d_in[1];
    const float* Wq    = (const float*)d_in[2];
    const float* bq    = (const float*)d_in[3];
    const float* Wk    = (const float*)d_in[4];
    const float* bk    = (const float*)d_in[5];
    const float* Wv    = (const float*)d_in[6];
    const float* bv    = (const float*)d_in[7];
    const float* gamma = (const float*)d_in[8];
    float* outp = (float*)d_out;

    // ws (bf16 shorts): xb 8MB | WT 0.75MB | Qb 2MB | Kb 2MB | Vt 8MB | maskbf 16KB
    unsigned short* xb = (unsigned short*)d_ws;
    unsigned short* WT = xb + (size_t)8192*512;
    unsigned short* Qb = WT + (size_t)768*512;
    unsigned short* Kb = Qb + (size_t)8192*128;
    unsigned short* Vt = Kb + (size_t)8192*128;
    unsigned short* maskbf = Vt + (size_t)2048*MSEQ;

    prep_kernel<<<2145, 256, 0, stream>>>(x, xb, Wq, Wk, Wv, WT, mask, maskbf);
    proj_mfma<<<dim3(6, 128), 256, 0, stream>>>(xb, WT, bq, bk, bv, mask, Qb, Kb, Vt);
    attn_mfma<<<dim3(8, 32), 512, 0, stream>>>(Qb, Kb, Vt, maskbf, gamma, outp);
}

// Round 14
// 150.629 us; speedup vs baseline: 1.0303x; 1.0303x over previous
//
#include <hip/hip_runtime.h>
#include <hip/hip_bf16.h>

#define MSEQ 2048

typedef __attribute__((ext_vector_type(8))) short short8;
typedef __attribute__((ext_vector_type(4))) short short4v;
typedef __attribute__((ext_vector_type(4))) float f32x4;

static __device__ __forceinline__ short bf16b(float f) {
    __hip_bfloat16 h = __float2bfloat16(f);   // RNE
    return *reinterpret_cast<short*>(&h);
}

// raw 2^x (input is pre-scaled by log2e at the K projection)
static __device__ __forceinline__ float fast_exp2(float x) {
    float r;
    asm("v_exp_f32 %0, %1" : "=v"(r) : "v"(x));
    return r;
}

// 16x16x16 bf16 MFMA (DQK=16 exact; score D-layout == PV A-frag layout)
static __device__ __forceinline__ f32x4 mfma16(short4v a, short4v b, f32x4 c) {
    return __builtin_amdgcn_mfma_f32_16x16x16bf16_1k(a, b, c, 0, 0, 0);
}

// async global->LDS, 16B per lane; LDS dest = wave-uniform base + lane*16
static __device__ __forceinline__ void gl_lds16(const void* g, void* l) {
    __builtin_amdgcn_global_load_lds(
        (const __attribute__((address_space(1))) unsigned int*)g,
        (__attribute__((address_space(3))) unsigned int*)l, 16, 0, 0);
}

// ---------------- prep: x fp32->bf16 | W->WT[n][k] bf16 | mask->bf16 ----------------
__global__ __launch_bounds__(256) void prep_kernel(
    const float* __restrict__ x, unsigned short* __restrict__ xb,
    const float* __restrict__ Wq, const float* __restrict__ Wk,
    const float* __restrict__ Wv, unsigned short* __restrict__ WT,
    const int* __restrict__ mask, unsigned short* __restrict__ maskbf)
{
    __shared__ unsigned short Ts[64*72];   // wtrans only
    const int bid = blockIdx.x;
    const int t = threadIdx.x;

    if (bid < 2048) {                      // ---- x cvt ----
        const size_t i = ((size_t)bid * 256 + t) * 8;
        const float4 a = *(const float4*)(x + i);
        const float4 b = *(const float4*)(x + i + 4);
        short8 o;
        o[0]=bf16b(a.x); o[1]=bf16b(a.y); o[2]=bf16b(a.z); o[3]=bf16b(a.w);
        o[4]=bf16b(b.x); o[5]=bf16b(b.y); o[6]=bf16b(b.z); o[7]=bf16b(b.w);
        *(short8*)(xb + i) = o;
        return;
    }
    if (bid == 2144) {                     // ---- mask -> bf16 (0/1 exact) ----
        #pragma unroll
        for (int j = 0; j < 8; ++j) {
            const int4 m4 = *(const int4*)(mask + (t*8 + j)*4);
            short4v o;
            o[0]=bf16b((float)m4.x); o[1]=bf16b((float)m4.y);
            o[2]=bf16b((float)m4.z); o[3]=bf16b((float)m4.w);
            *(short4v*)(maskbf + (t*8 + j)*4) = o;
        }
        return;
    }
    // ---- wtrans ----
    const int idx = bid - 2048;            // 96 blocks
    const int nt = idx >> 3;
    const int kt = idx & 7;
    const int k0 = kt*64;

    const float* W; int ld, n0;
    if (nt < 2)      { W = Wq; ld = 128; n0 = nt*64; }
    else if (nt < 4) { W = Wk; ld = 128; n0 = (nt-2)*64; }
    else             { W = Wv; ld = 512; n0 = (nt-4)*64; }

    #pragma unroll
    for (int s = 0; s < 4; ++s) {
        const int lin = s*256 + t;
        const int krow = lin >> 4, ng = lin & 15;
        const float4 v = *(const float4*)(W + (size_t)(k0+krow)*ld + n0 + ng*4);
        Ts[(ng*4+0)*72 + krow] = (unsigned short)bf16b(v.x);
        Ts[(ng*4+1)*72 + krow] = (unsigned short)bf16b(v.y);
        Ts[(ng*4+2)*72 + krow] = (unsigned short)bf16b(v.z);
        Ts[(ng*4+3)*72 + krow] = (unsigned short)bf16b(v.w);
    }
    __syncthreads();
    #pragma unroll
    for (int s = 0; s < 2; ++s) {
        const int lin = s*256 + t;
        const int nrow = lin >> 3, kg = lin & 7;
        *(short8*)(WT + (size_t)(nt*64 + nrow)*512 + k0 + kg*8) = *(const short8*)&Ts[nrow*72 + kg*8];
    }
}

// ---------------- Fused projection GEMM, bf16 MFMA, 64x128 tiles (r11 verbatim) ----------------
__global__ __launch_bounds__(256, 3) void proj_mfma(
    const unsigned short* __restrict__ xb, const unsigned short* __restrict__ WT,
    const float* __restrict__ bq, const float* __restrict__ bk, const float* __restrict__ bv,
    const int* __restrict__ mask,
    unsigned short* __restrict__ Qb, unsigned short* __restrict__ Kb, unsigned short* __restrict__ Vt)
{
    const int g0 = blockIdx.y * 6 + blockIdx.x;   // 768 blocks, 768%8==0
    const int xcd = g0 & 7, idx = g0 >> 3;        // idx in [0,96)
    const int nt = idx / 16;                      // 0..5 (0=Q,1=K,2..5=V)
    const int r0 = (xcd * 16 + (idx & 15)) * 64;  // m tile (bijective)
    const int n0 = nt * 128;
    const int t = threadIdx.x, w = t >> 6, lane = t & 63, l15 = lane & 15, quad = lane >> 4;
    const int qh = w >> 1, chh = w & 1;

    __shared__ short smem[12288];     // As[2][2048] | Bs[2][4096]; Ts aliases (<=9216)
    short* As = smem;
    short* Bs = smem + 4096;

    f32x4 acc[2][4];
    #pragma unroll
    for (int i = 0; i < 2; ++i)
        #pragma unroll
        for (int j = 0; j < 4; ++j) acc[i][j] = {0.f,0.f,0.f,0.f};

    const int arow = lane >> 2, akg = lane & 3;

#define PROJ_STAGE(BUFI, KK) {                                                          \
    gl_lds16(xb + (size_t)(r0 + w*16 + arow)*512 + (KK) + akg*8,                        \
             (char*)As + (BUFI)*4096 + w*1024);                                         \
    gl_lds16(WT + (size_t)(n0 + w*16 + arow)*512 + (KK) + akg*8,                        \
             (char*)Bs + (BUFI)*8192 + w*1024);                                         \
    gl_lds16(WT + (size_t)(n0 + 64 + w*16 + arow)*512 + (KK) + akg*8,                   \
             (char*)Bs + (BUFI)*8192 + 4096 + w*1024);                                  \
}

    PROJ_STAGE(0, 0)
    __syncthreads();

    #pragma unroll 2
    for (int kp = 0; kp < 16; ++kp) {
        const int cur = kp & 1;
        if (kp < 15) PROJ_STAGE(cur ^ 1, (kp+1)*32)
        short8 Af[2], Bf[4];
        #pragma unroll
        for (int i = 0; i < 2; ++i)
            Af[i] = *(const short8*)&As[cur*2048 + (qh*32 + i*16 + l15)*32 + quad*8];
        #pragma unroll
        for (int j = 0; j < 4; ++j)
            Bf[j] = *(const short8*)&Bs[cur*4096 + (chh*64 + j*16 + l15)*32 + quad*8];
        #pragma unroll
        for (int i = 0; i < 2; ++i)
            #pragma unroll
            for (int j = 0; j < 4; ++j)
                acc[i][j] = __builtin_amdgcn_mfma_f32_16x16x32_bf16(Af[i], Bf[j], acc[i][j], 0, 0, 0);
        __syncthreads();
    }

    const float* bias = (nt == 0) ? bq : (nt == 1) ? bk : (bv + (nt-2)*128);
    const float kscale = (nt == 1) ? 0.36067376022224085f : 1.0f;  // 0.25 * log2(e)
    float bj[4];
    #pragma unroll
    for (int j = 0; j < 4; ++j) bj[j] = bias[chh*64 + j*16 + l15];

    const int bb = r0 >> 11, key0 = r0 & 2047;
    short* Ts = smem;
    if (nt < 2) {
        #pragma unroll
        for (int i = 0; i < 2; ++i)
            #pragma unroll
            for (int j = 0; j < 4; ++j)
                #pragma unroll
                for (int r = 0; r < 4; ++r)
                    Ts[(qh*32 + i*16 + quad*4 + r)*136 + chh*64 + j*16 + l15] =
                        bf16b((acc[i][j][r] + bj[j]) * kscale);
    } else {
        float mv[2][4];
        #pragma unroll
        for (int i = 0; i < 2; ++i)
            #pragma unroll
            for (int r = 0; r < 4; ++r)
                mv[i][r] = (float)mask[bb*MSEQ + key0 + qh*32 + i*16 + quad*4 + r];
        #pragma unroll
        for (int i = 0; i < 2; ++i)
            #pragma unroll
            for (int j = 0; j < 4; ++j)
                #pragma unroll
                for (int r = 0; r < 4; ++r)
                    Ts[(chh*64 + j*16 + l15)*72 + qh*32 + i*16 + quad*4 + r] =
                        bf16b((acc[i][j][r] + bj[j]) * mv[i][r]);
    }
    __syncthreads();

    if (nt < 2) {
        unsigned short* Out = (nt == 0) ? Qb : Kb;
        #pragma unroll
        for (int s = 0; s < 4; ++s) {
            const int lin = s*256 + t, row = lin >> 4, seg = lin & 15;
            *(short8*)(Out + (size_t)(r0+row)*128 + seg*8) = *(const short8*)&Ts[row*136 + seg*8];
        }
    } else {
        const int chBase = (nt-2)*128;
        #pragma unroll
        for (int s = 0; s < 4; ++s) {
            const int lin = s*256 + t, row = lin >> 3, seg = lin & 7;
            *(short8*)(Vt + ((size_t)(bb*512 + chBase + row))*MSEQ + key0 + seg*8) =
                *(const short8*)&Ts[row*72 + seg*8];
        }
    }
#undef PROJ_STAGE
}

// ---------------- Fused masked attention: 4 waves x 32q x 64ch, 2 blocks/CU ----------------
// Round-14: r13's q-expansion compute (two 16-q MFMA groups/wave sharing K/V/mask
// frags -> per-q LDS read volume halved, CONFIRMED: conflicts 10.49M->5.24M) in
// r7's proven 4-wave staging geometry. Block = 128 q (256 thr), grid 16x32 = 512
// = 2 blocks/CU — restores cross-block interleave at the barriers (r13's 1 blk/CU
// convoyed: all utilizations dropped ~10%). Same race-free
// STAGE(cur^1)->COMPUTE(cur)->__syncthreads skeleton.
__global__ __launch_bounds__(256, 2) void attn_mfma(
    const unsigned short* __restrict__ Qb, const unsigned short* __restrict__ Kb,
    const unsigned short* __restrict__ Vt, const unsigned short* __restrict__ maskbf,
    const float* __restrict__ gamma, float* __restrict__ out)
{
    // XCD-aware bijective remap (512 % 8 == 0): XCD x owns bh in [x*4, x*4+4)
    const int bid = blockIdx.y * 16 + blockIdx.x;   // 512 blocks
    const int lin = (bid & 7) * 64 + (bid >> 3);
    const int mt = lin & 15, bh = lin >> 4;
    const int b  = bh >> 3, h = bh & 7;
    const int m0 = mt * 128;
    const int t  = threadIdx.x;
    const int w = t >> 6, lane = t & 63, l15 = lane & 15, quad = lane >> 4;
    const int mq = m0 + w*32;            // this wave's 32 q rows (2 groups of 16)

    __shared__ __align__(16) short Ks[2][64*16];   // [key][16 d], granule-swizzled
    __shared__ __align__(16) short Vs[2][64*64];   // [ch][64 key], granule-swizzled, pre-masked
    __shared__ __align__(16) short Msb[2][64];     // bf16 mask per key

    // Q B-frags for the two 16-q groups: n=q=l15, k=d=quad*4+j
    short4v qf[2];
    #pragma unroll
    for (int g = 0; g < 2; ++g)
        qf[g] = *(const short4v*)(Qb + (size_t)(b*MSEQ + mq + g*16 + l15)*128 + h*16 + quad*4);

    // staging sources (per-lane, swizzle pre-applied on the global side)
    const unsigned short* Kg = Kb + (size_t)(b*MSEQ + (lane>>1))*128 + h*16
                              + (((lane&1) ^ ((lane>>3)&1))*8);
    // wave w stages V ch-rows 16w..16w+15 via two 1KB DMAs (r7 pattern)
    const int vj0 = 2*w;
    const unsigned short* Vg0 = Vt + (size_t)(b*512 + h*64 + vj0*8 + (lane>>3))*MSEQ
                               + (((lane&7) ^ ((lane>>3)&7)) * 8);
    const unsigned short* Vg1 = Vg0 + (size_t)8*MSEQ;
    const unsigned short* Mgb = maskbf + b*MSEQ + lane*8;   // w==2, lanes<8

#define ATT_STAGE(BUFI, KN) {                                                        \
    gl_lds16(Vg0 + (KN), &Vs[BUFI][vj0*512]);                                        \
    gl_lds16(Vg1 + (KN), &Vs[BUFI][(vj0+1)*512]);                                    \
    if (w < 2)                   gl_lds16(Kg + (size_t)((KN) + w*32)*128, &Ks[BUFI][w*32*16]); \
    else if (w == 2 && lane < 8) gl_lds16(Mgb + (KN), &Msb[BUFI][0]);                \
}

    // hoisted LDS read offsets (bytes)
    const char* KsB = (const char*)&Ks[0][0];
    const char* VsB = (const char*)&Vs[0][0];
    const char* MsB = (const char*)&Msb[0][0];
    const int kofs = l15*32 + (((quad>>1) ^ ((l15>>2)&1))*16) + (quad&1)*8;
    const int mofs = quad*8;
    int vb[4];
    #pragma unroll
    for (int v = 0; v < 4; ++v) {
        const int ch = v*16 + l15;
        vb[v] = ch*128 + (((quad>>1) ^ (ch&7))*16) + (quad&1)*8;
    }

    f32x4 O[2][4];      // [q-group][v]
    #pragma unroll
    for (int g = 0; g < 2; ++g)
        #pragma unroll
        for (int v = 0; v < 4; ++v) O[g][v] = {0.f,0.f,0.f,0.f};
    f32x4 WS[2] = {{0.f,0.f,0.f,0.f},{0.f,0.f,0.f,0.f}};

    ATT_STAGE(0, 0)
    __syncthreads();

    #pragma unroll 2
    for (int kt = 0; kt < 32; ++kt) {
        const int cur = kt & 1;
        if (kt < 31) ATT_STAGE(cur ^ 1, (kt+1)*64)

        const char* Kc = KsB + cur*2048;
        const char* Vc = VsB + cur*8192;
        const char* Mc = MsB + cur*128;

        __builtin_amdgcn_s_setprio(1);
        // batch K and mask fragments for all 4 s-slices (independent ds_reads)
        short4v kfs[4], mkfs[4];
        #pragma unroll
        for (int s = 0; s < 4; ++s) {
            kfs[s]  = *(const short4v*)(Kc + kofs + s*512);
            mkfs[s] = *(const short4v*)(Mc + mofs + s*32);
        }

        #pragma unroll
        for (int s = 0; s < 4; ++s) {
            // V fragments once per s-slice; reused by both q-groups (the q-expansion win)
            short4v vfs[4];
            #pragma unroll
            for (int v = 0; v < 4; ++v)
                vfs[v] = *(const short4v*)(Vc + (vb[v] ^ (s*32)));
            #pragma unroll
            for (int g = 0; g < 2; ++g) {
                f32x4 sc = {0.f,0.f,0.f,0.f};
                sc = mfma16(kfs[s], qf[g], sc);
                // lane: q=l15 (group g), keys = s*16+quad*4+r; K pre-scaled by 0.25*log2e
                const float w0 = fast_exp2(fmaxf(sc[0], 0.f));
                const float w1 = fast_exp2(fmaxf(sc[1], 0.f));
                const float w2 = fast_exp2(fmaxf(sc[2], 0.f));
                const float w3 = fast_exp2(fmaxf(sc[3], 0.f));
                const __hip_bfloat162 p01 = __float22bfloat162_rn(make_float2(w0, w1));
                const __hip_bfloat162 p23 = __float22bfloat162_rn(make_float2(w2, w3));
                unsigned u01, u23;
                __builtin_memcpy(&u01, &p01, 4);
                __builtin_memcpy(&u23, &p23, 4);
                uint2 pku; pku.x = u01; pku.y = u23;
                short4v pf;
                __builtin_memcpy(&pf, &pku, 8);
                WS[g] = mfma16(pf, mkfs[s], WS[g]);     // wsum: D row q=quad*4+r on this lane
                #pragma unroll
                for (int v = 0; v < 4; ++v)
                    O[g][v] = mfma16(pf, vfs[v], O[g][v]);   // V pre-masked
            }
        }
        __builtin_amdgcn_s_setprio(0);
        __syncthreads();   // full drain: reads of cur done; stage of cur^1 landed
    }

    // WS[g][r] = masked wsum for q = mq + g*16 + quad*4 + r — same lane that owns O[g][.][r].
    const float gm = gamma[0];
    #pragma unroll
    for (int g = 0; g < 2; ++g) {
        float inv[4];
        #pragma unroll
        for (int r = 0; r < 4; ++r) inv[r] = gm / fmaxf(WS[g][r], 1e-20f);
        float* op = out + (size_t)(b*MSEQ + mq + g*16 + quad*4)*512 + h*64 + l15;
        #pragma unroll
        for (int r = 0; r < 4; ++r) {
            op[(size_t)r*512 +  0] = O[g][0][r] * inv[r];
            op[(size_t)r*512 + 16] = O[g][1][r] * inv[r];
            op[(size_t)r*512 + 32] = O[g][2][r] * inv[r];
            op[(size_t)r*512 + 48] = O[g][3][r] * inv[r];
        }
    }
#undef ATT_STAGE
}

extern "C" void kernel_launch(void* const* d_in, const int* in_sizes, int n_in,
                              void* d_out, int out_size, void* d_ws, size_t ws_size,
                              hipStream_t stream) {
    const float* x     = (const float*)d_in[0];
    const int*   mask  = (const int*)  d_in[1];
    const float* Wq    = (const float*)d_in[2];
    const float* bq    = (const float*)d_in[3];
    const float* Wk    = (const float*)d_in[4];
    const float* bk    = (const float*)d_in[5];
    const float* Wv    = (const float*)d_in[6];
    const float* bv    = (const float*)d_in[7];
    const float* gamma = (const float*)d_in[8];
    float* outp = (float*)d_out;

    // ws (bf16 shorts): xb 8MB | WT 0.75MB | Qb 2MB | Kb 2MB | Vt 8MB | maskbf 16KB
    unsigned short* xb = (unsigned short*)d_ws;
    unsigned short* WT = xb + (size_t)8192*512;
    unsigned short* Qb = WT + (size_t)768*512;
    unsigned short* Kb = Qb + (size_t)8192*128;
    unsigned short* Vt = Kb + (size_t)8192*128;
    unsigned short* maskbf = Vt + (size_t)2048*MSEQ;

    prep_kernel<<<2145, 256, 0, stream>>>(x, xb, Wq, Wk, Wv, WT, mask, maskbf);
    proj_mfma<<<dim3(6, 128), 256, 0, stream>>>(xb, WT, bq, bk, bv, mask, Qb, Kb, Vt);
    attn_mfma<<<dim3(16, 32), 256, 0, stream>>>(Qb, Kb, Vt, maskbf, gamma, outp);
}

// Round 15
// 148.037 us; speedup vs baseline: 1.0484x; 1.0175x over previous
//
#include <hip/hip_runtime.h>
#include <hip/hip_bf16.h>

#define MSEQ 2048

typedef __attribute__((ext_vector_type(8))) short short8;
typedef __attribute__((ext_vector_type(4))) short short4v;
typedef __attribute__((ext_vector_type(4))) float f32x4;

static __device__ __forceinline__ short bf16b(float f) {
    __hip_bfloat16 h = __float2bfloat16(f);   // RNE
    return *reinterpret_cast<short*>(&h);
}

// raw 2^x (input is pre-scaled by log2e at the K projection)
static __device__ __forceinline__ float fast_exp2(float x) {
    float r;
    asm("v_exp_f32 %0, %1" : "=v"(r) : "v"(x));
    return r;
}

// 16x16x16 bf16 MFMA (DQK=16 exact; score D-layout == PV A-frag layout)
static __device__ __forceinline__ f32x4 mfma16(short4v a, short4v b, f32x4 c) {
    return __builtin_amdgcn_mfma_f32_16x16x16bf16_1k(a, b, c, 0, 0, 0);
}

// async global->LDS, 16B per lane; LDS dest = wave-uniform base + lane*16
static __device__ __forceinline__ void gl_lds16(const void* g, void* l) {
    __builtin_amdgcn_global_load_lds(
        (const __attribute__((address_space(1))) unsigned int*)g,
        (__attribute__((address_space(3))) unsigned int*)l, 16, 0, 0);
}

// ---------------- prep: x fp32->bf16 | W->WT[n][k] bf16 | mask->bf16 ----------------
// Round-15: xcvt loads made lane-contiguous (was stride-32B interleaved — every
// 128B line fetched twice at half density). Lane t reads float4 at base+t*16B,
// second batch at +4KB; stores 8B contiguous. Same grid, same output layout.
__global__ __launch_bounds__(256) void prep_kernel(
    const float* __restrict__ x, unsigned short* __restrict__ xb,
    const float* __restrict__ Wq, const float* __restrict__ Wk,
    const float* __restrict__ Wv, unsigned short* __restrict__ WT,
    const int* __restrict__ mask, unsigned short* __restrict__ maskbf)
{
    __shared__ unsigned short Ts[64*72];   // wtrans only
    const int bid = blockIdx.x;
    const int t = threadIdx.x;

    if (bid < 2048) {                      // ---- x cvt (coalesced) ----
        const size_t base = (size_t)bid * 2048;      // floats; 2048*2048 = 4.19M total
        const float4 a = *(const float4*)(x + base + t*4);
        const float4 b = *(const float4*)(x + base + 1024 + t*4);
        short4v oa, ob;
        oa[0]=bf16b(a.x); oa[1]=bf16b(a.y); oa[2]=bf16b(a.z); oa[3]=bf16b(a.w);
        ob[0]=bf16b(b.x); ob[1]=bf16b(b.y); ob[2]=bf16b(b.z); ob[3]=bf16b(b.w);
        *(short4v*)(xb + base + t*4) = oa;
        *(short4v*)(xb + base + 1024 + t*4) = ob;
        return;
    }
    if (bid == 2144) {                     // ---- mask -> bf16 (0/1 exact) ----
        #pragma unroll
        for (int j = 0; j < 8; ++j) {
            const int4 m4 = *(const int4*)(mask + (t*8 + j)*4);
            short4v o;
            o[0]=bf16b((float)m4.x); o[1]=bf16b((float)m4.y);
            o[2]=bf16b((float)m4.z); o[3]=bf16b((float)m4.w);
            *(short4v*)(maskbf + (t*8 + j)*4) = o;
        }
        return;
    }
    // ---- wtrans ----
    const int idx = bid - 2048;            // 96 blocks
    const int nt = idx >> 3;
    const int kt = idx & 7;
    const int k0 = kt*64;

    const float* W; int ld, n0;
    if (nt < 2)      { W = Wq; ld = 128; n0 = nt*64; }
    else if (nt < 4) { W = Wk; ld = 128; n0 = (nt-2)*64; }
    else             { W = Wv; ld = 512; n0 = (nt-4)*64; }

    #pragma unroll
    for (int s = 0; s < 4; ++s) {
        const int lin = s*256 + t;
        const int krow = lin >> 4, ng = lin & 15;
        const float4 v = *(const float4*)(W + (size_t)(k0+krow)*ld + n0 + ng*4);
        Ts[(ng*4+0)*72 + krow] = (unsigned short)bf16b(v.x);
        Ts[(ng*4+1)*72 + krow] = (unsigned short)bf16b(v.y);
        Ts[(ng*4+2)*72 + krow] = (unsigned short)bf16b(v.z);
        Ts[(ng*4+3)*72 + krow] = (unsigned short)bf16b(v.w);
    }
    __syncthreads();
    #pragma unroll
    for (int s = 0; s < 2; ++s) {
        const int lin = s*256 + t;
        const int nrow = lin >> 3, kg = lin & 7;
        *(short8*)(WT + (size_t)(nt*64 + nrow)*512 + k0 + kg*8) = *(const short8*)&Ts[nrow*72 + kg*8];
    }
}

// ---------------- Fused projection GEMM, bf16 MFMA, 64x128 tiles (r11 verbatim) ----------------
__global__ __launch_bounds__(256, 3) void proj_mfma(
    const unsigned short* __restrict__ xb, const unsigned short* __restrict__ WT,
    const float* __restrict__ bq, const float* __restrict__ bk, const float* __restrict__ bv,
    const int* __restrict__ mask,
    unsigned short* __restrict__ Qb, unsigned short* __restrict__ Kb, unsigned short* __restrict__ Vt)
{
    const int g0 = blockIdx.y * 6 + blockIdx.x;   // 768 blocks, 768%8==0
    const int xcd = g0 & 7, idx = g0 >> 3;        // idx in [0,96)
    const int nt = idx / 16;                      // 0..5 (0=Q,1=K,2..5=V)
    const int r0 = (xcd * 16 + (idx & 15)) * 64;  // m tile (bijective)
    const int n0 = nt * 128;
    const int t = threadIdx.x, w = t >> 6, lane = t & 63, l15 = lane & 15, quad = lane >> 4;
    const int qh = w >> 1, chh = w & 1;

    __shared__ short smem[12288];     // As[2][2048] | Bs[2][4096]; Ts aliases (<=9216)
    short* As = smem;
    short* Bs = smem + 4096;

    f32x4 acc[2][4];
    #pragma unroll
    for (int i = 0; i < 2; ++i)
        #pragma unroll
        for (int j = 0; j < 4; ++j) acc[i][j] = {0.f,0.f,0.f,0.f};

    const int arow = lane >> 2, akg = lane & 3;

#define PROJ_STAGE(BUFI, KK) {                                                          \
    gl_lds16(xb + (size_t)(r0 + w*16 + arow)*512 + (KK) + akg*8,                        \
             (char*)As + (BUFI)*4096 + w*1024);                                         \
    gl_lds16(WT + (size_t)(n0 + w*16 + arow)*512 + (KK) + akg*8,                        \
             (char*)Bs + (BUFI)*8192 + w*1024);                                         \
    gl_lds16(WT + (size_t)(n0 + 64 + w*16 + arow)*512 + (KK) + akg*8,                   \
             (char*)Bs + (BUFI)*8192 + 4096 + w*1024);                                  \
}

    PROJ_STAGE(0, 0)
    __syncthreads();

    #pragma unroll 2
    for (int kp = 0; kp < 16; ++kp) {
        const int cur = kp & 1;
        if (kp < 15) PROJ_STAGE(cur ^ 1, (kp+1)*32)
        short8 Af[2], Bf[4];
        #pragma unroll
        for (int i = 0; i < 2; ++i)
            Af[i] = *(const short8*)&As[cur*2048 + (qh*32 + i*16 + l15)*32 + quad*8];
        #pragma unroll
        for (int j = 0; j < 4; ++j)
            Bf[j] = *(const short8*)&Bs[cur*4096 + (chh*64 + j*16 + l15)*32 + quad*8];
        #pragma unroll
        for (int i = 0; i < 2; ++i)
            #pragma unroll
            for (int j = 0; j < 4; ++j)
                acc[i][j] = __builtin_amdgcn_mfma_f32_16x16x32_bf16(Af[i], Bf[j], acc[i][j], 0, 0, 0);
        __syncthreads();
    }

    const float* bias = (nt == 0) ? bq : (nt == 1) ? bk : (bv + (nt-2)*128);
    const float kscale = (nt == 1) ? 0.36067376022224085f : 1.0f;  // 0.25 * log2(e)
    float bj[4];
    #pragma unroll
    for (int j = 0; j < 4; ++j) bj[j] = bias[chh*64 + j*16 + l15];

    const int bb = r0 >> 11, key0 = r0 & 2047;
    short* Ts = smem;
    if (nt < 2) {
        #pragma unroll
        for (int i = 0; i < 2; ++i)
            #pragma unroll
            for (int j = 0; j < 4; ++j)
                #pragma unroll
                for (int r = 0; r < 4; ++r)
                    Ts[(qh*32 + i*16 + quad*4 + r)*136 + chh*64 + j*16 + l15] =
                        bf16b((acc[i][j][r] + bj[j]) * kscale);
    } else {
        float mv[2][4];
        #pragma unroll
        for (int i = 0; i < 2; ++i)
            #pragma unroll
            for (int r = 0; r < 4; ++r)
                mv[i][r] = (float)mask[bb*MSEQ + key0 + qh*32 + i*16 + quad*4 + r];
        #pragma unroll
        for (int i = 0; i < 2; ++i)
            #pragma unroll
            for (int j = 0; j < 4; ++j)
                #pragma unroll
                for (int r = 0; r < 4; ++r)
                    Ts[(chh*64 + j*16 + l15)*72 + qh*32 + i*16 + quad*4 + r] =
                        bf16b((acc[i][j][r] + bj[j]) * mv[i][r]);
    }
    __syncthreads();

    if (nt < 2) {
        unsigned short* Out = (nt == 0) ? Qb : Kb;
        #pragma unroll
        for (int s = 0; s < 4; ++s) {
            const int lin = s*256 + t, row = lin >> 4, seg = lin & 15;
            *(short8*)(Out + (size_t)(r0+row)*128 + seg*8) = *(const short8*)&Ts[row*136 + seg*8];
        }
    } else {
        const int chBase = (nt-2)*128;
        #pragma unroll
        for (int s = 0; s < 4; ++s) {
            const int lin = s*256 + t, row = lin >> 3, seg = lin & 7;
            *(short8*)(Vt + ((size_t)(bb*512 + chBase + row))*MSEQ + key0 + seg*8) =
                *(const short8*)&Ts[row*72 + seg*8];
        }
    }
#undef PROJ_STAGE
}

// ---------------- Fused masked attention: 8 waves x 16q x 64ch (r11 verbatim, best @57.2) ----------------
// Ledger r7..r14: 59.1/80.5/58.8/57.5/61.6/59.0 — r11 is the floor for this
// algorithm family. VALU(26us)+MFMA(19.5us) additive under barrier lockstep;
// LDS-volume halving (r13/r14, conflicts 10.49M->5.24M confirmed) moved nothing.
__global__ __launch_bounds__(512, 4) void attn_mfma(
    const unsigned short* __restrict__ Qb, const unsigned short* __restrict__ Kb,
    const unsigned short* __restrict__ Vt, const unsigned short* __restrict__ maskbf,
    const float* __restrict__ gamma, float* __restrict__ out)
{
    // XCD-aware bijective remap (512 % 8 == 0): XCD x owns bh in [x*4, x*4+4)
    const int bid = blockIdx.y * 16 + blockIdx.x;
    const int lin = (bid & 7) * 64 + (bid >> 3);
    const int mt = lin & 15, bh = lin >> 4;
    const int b  = bh >> 3, h = bh & 7;
    const int m0 = mt * 128;
    const int t  = threadIdx.x;
    const int w = t >> 6, lane = t & 63, l15 = lane & 15, quad = lane >> 4;
    const int mq = m0 + w*16;            // this wave's 16 q rows

    __shared__ __align__(16) short Ks[2][64*16];   // [key][16 d], granule-swizzled
    __shared__ __align__(16) short Vs[2][64*64];   // [ch][64 key], granule-swizzled, pre-masked
    __shared__ __align__(16) short Msb[2][64];     // bf16 mask per key

    // Q B-frag: n=q=l15, k=d=quad*4+j
    const short4v qf = *(const short4v*)(Qb + (size_t)(b*MSEQ + mq + l15)*128 + h*16 + quad*4);

    // staging sources (per-lane, swizzle pre-applied on the global side)
    const unsigned short* Kg = Kb + (size_t)(b*MSEQ + (lane>>1))*128 + h*16
                              + (((lane&1) ^ ((lane>>3)&1))*8);
    // wave w stages V ch-rows w*8 .. w*8+7 (one 1KB DMA per wave)
    const unsigned short* Vg = Vt + (size_t)(b*512 + h*64 + w*8 + (lane>>3))*MSEQ
                              + (((lane&7) ^ ((lane>>3)&7)) * 8);
    const unsigned short* Mgb = maskbf + b*MSEQ + lane*8;   // w==2, lanes<8

#define ATT_STAGE(BUFI, KN) {                                                        \
    gl_lds16(Vg + (KN), &Vs[BUFI][w*512]);                                           \
    if (w < 2)                   gl_lds16(Kg + (size_t)((KN) + w*32)*128, &Ks[BUFI][w*32*16]); \
    else if (w == 2 && lane < 8) gl_lds16(Mgb + (KN), &Msb[BUFI][0]);                \
}

    // hoisted LDS read offsets (bytes)
    const char* KsB = (const char*)&Ks[0][0];
    const char* VsB = (const char*)&Vs[0][0];
    const char* MsB = (const char*)&Msb[0][0];
    const int kofs = l15*32 + (((quad>>1) ^ ((l15>>2)&1))*16) + (quad&1)*8;
    const int mofs = quad*8;
    int vb[4];
    #pragma unroll
    for (int v = 0; v < 4; ++v) {
        const int ch = v*16 + l15;
        vb[v] = ch*128 + (((quad>>1) ^ (ch&7))*16) + (quad&1)*8;
    }

    f32x4 O[4];
    #pragma unroll
    for (int v = 0; v < 4; ++v) O[v] = {0.f,0.f,0.f,0.f};
    f32x4 WS = {0.f,0.f,0.f,0.f};

    ATT_STAGE(0, 0)
    __syncthreads();

    #pragma unroll 2
    for (int kt = 0; kt < 32; ++kt) {
        const int cur = kt & 1;
        if (kt < 31) ATT_STAGE(cur ^ 1, (kt+1)*64)

        const char* Kc = KsB + cur*2048;
        const char* Vc = VsB + cur*8192;
        const char* Mc = MsB + cur*128;

        __builtin_amdgcn_s_setprio(1);
        // batch K and mask fragments for all 4 s-slices (independent ds_reads)
        short4v kfs[4], mkfs[4];
        #pragma unroll
        for (int s = 0; s < 4; ++s) {
            kfs[s]  = *(const short4v*)(Kc + kofs + s*512);
            mkfs[s] = *(const short4v*)(Mc + mofs + s*32);
        }

        #pragma unroll
        for (int s = 0; s < 4; ++s) {
            f32x4 sc = {0.f,0.f,0.f,0.f};
            sc = mfma16(kfs[s], qf, sc);
            // lane: q=l15, keys = s*16+quad*4+r; K pre-scaled by 0.25*log2e
            const float w0 = fast_exp2(fmaxf(sc[0], 0.f));
            const float w1 = fast_exp2(fmaxf(sc[1], 0.f));
            const float w2 = fast_exp2(fmaxf(sc[2], 0.f));
            const float w3 = fast_exp2(fmaxf(sc[3], 0.f));
            // packed RNE conversion (library; identical numerics to bf16b)
            const __hip_bfloat162 p01 = __float22bfloat162_rn(make_float2(w0, w1));
            const __hip_bfloat162 p23 = __float22bfloat162_rn(make_float2(w2, w3));
            unsigned u01, u23;
            __builtin_memcpy(&u01, &p01, 4);
            __builtin_memcpy(&u23, &p23, 4);
            uint2 pku; pku.x = u01; pku.y = u23;
            short4v pf;
            __builtin_memcpy(&pf, &pku, 8);
            WS = mfma16(pf, mkfs[s], WS);          // wsum: D row q = quad*4+r on this lane
            #pragma unroll
            for (int v = 0; v < 4; ++v) {
                const short4v vf = *(const short4v*)(Vc + (vb[v] ^ (s*32)));
                O[v] = mfma16(pf, vf, O[v]);       // V pre-masked -> masked keys add 0
            }
        }
        __builtin_amdgcn_s_setprio(0);
        __syncthreads();   // full drain: reads of cur done; stage of cur^1 landed
    }

    // WS[r] = masked wsum for q = quad*4+r — same lane that owns O[.][r].
    const float g = gamma[0];
    float inv[4];
    #pragma unroll
    for (int r = 0; r < 4; ++r) inv[r] = g / fmaxf(WS[r], 1e-20f);

    float* op = out + (size_t)(b*MSEQ + mq + quad*4)*512 + h*64 + l15;
    #pragma unroll
    for (int r = 0; r < 4; ++r) {
        op[(size_t)r*512 +  0] = O[0][r] * inv[r];
        op[(size_t)r*512 + 16] = O[1][r] * inv[r];
        op[(size_t)r*512 + 32] = O[2][r] * inv[r];
        op[(size_t)r*512 + 48] = O[3][r] * inv[r];
    }
#undef ATT_STAGE
}

extern "C" void kernel_launch(void* const* d_in, const int* in_sizes, int n_in,
                              void* d_out, int out_size, void* d_ws, size_t ws_size,
                              hipStream_t stream) {
    const float* x     = (const float*)d_in[0];
    const int*   mask  = (const int*)  d_in[1];
    const float* Wq    = (const float*)d_in[2];
    const float* bq    = (const float*)d_in[3];
    const float* Wk    = (const float*)d_in[4];
    const float* bk    = (const float*)d_in[5];
    const float* Wv    = (const float*)d_in[6];
    const float* bv    = (const float*)d_in[7];
    const float* gamma = (const float*)d_in[8];
    float* outp = (float*)d_out;

    // ws (bf16 shorts): xb 8MB | WT 0.75MB | Qb 2MB | Kb 2MB | Vt 8MB | maskbf 16KB
    unsigned short* xb = (unsigned short*)d_ws;
    unsigned short* WT = xb + (size_t)8192*512;
    unsigned short* Qb = WT + (size_t)768*512;
    unsigned short* Kb = Qb + (size_t)8192*128;
    unsigned short* Vt = Kb + (size_t)8192*128;
    unsigned short* maskbf = Vt + (size_t)2048*MSEQ;

    prep_kernel<<<2145, 256, 0, stream>>>(x, xb, Wq, Wk, Wv, WT, mask, maskbf);
    proj_mfma<<<dim3(6, 128), 256, 0, stream>>>(xb, WT, bq, bk, bv, mask, Qb, Kb, Vt);
    attn_mfma<<<dim3(16, 32), 512, 0, stream>>>(Qb, Kb, Vt, maskbf, gamma, outp);
}